// Round 3
// baseline (1759.169 us; speedup 1.0000x reference)
//
#include <hip/hip_runtime.h>
#include <math.h>

#define NEG 0.2f

__device__ __forceinline__ float leaky(float x){ return x >= 0.f ? x : NEG*x; }

// monotonic float<->uint key for atomicMax on floats (all-finite inputs)
__device__ __forceinline__ unsigned fkey(float x){
    unsigned u = __float_as_uint(x);
    return (u & 0x80000000u) ? ~u : (u | 0x80000000u);
}
__device__ __forceinline__ float funkey(unsigned k){
    unsigned u = (k & 0x80000000u) ? (k & 0x7FFFFFFFu) : ~k;
    return __uint_as_float(u);
}

// h1[n][c] = sum_i x[n][i] * W1[i][c]   (thread per output element)
__global__ void n_gemm1(const float* __restrict__ x, const float* __restrict__ W1,
                        float* __restrict__ h1, int N){
    int idx = blockIdx.x*256 + threadIdx.x;
    if (idx >= N*64) return;
    int n = idx >> 6, c = idx & 63;
    const float* xr = x + (size_t)n*128;
    float acc = 0.f;
    for (int i = 0; i < 128; ++i) acc = fmaf(xr[i], W1[i*64 + c], acc);
    h1[idx] = acc;
}

// s[n] = h[n]·a_s, d[n] = h[n]·a_d   (thread per node)
__global__ void n_sd(const float* __restrict__ h, const float* __restrict__ a_s,
                     const float* __restrict__ a_d, float* __restrict__ s,
                     float* __restrict__ d, int N, int C){
    int n = blockIdx.x*256 + threadIdx.x;
    if (n >= N) return;
    float sv = 0.f, dv = 0.f;
    for (int c = 0; c < C; ++c){
        float hv = h[(size_t)n*C + c];
        sv = fmaf(hv, a_s[c], sv);
        dv = fmaf(hv, a_d[c], dv);
    }
    s[n] = sv; d[n] = dv;
}

// e[i] = leaky(s[src]+d[dst]); segment_max via atomicMax on keys.
// edges i<E from edge_index, i>=E are self-loops (src=dst=i-E).
__global__ void n_score(const int* __restrict__ ei, const float* __restrict__ s,
                        const float* __restrict__ d, float* __restrict__ e,
                        unsigned* __restrict__ mkey, int E, int ET){
    int i = blockIdx.x*256 + threadIdx.x;
    if (i >= ET) return;
    int src = (i < E) ? ei[i]     : (i - E);
    int dst = (i < E) ? ei[E + i] : (i - E);
    float ev = leaky(s[src] + d[dst]);
    e[i] = ev;
    atomicMax(&mkey[dst], fkey(ev));
}

// p[i] = exp(e[i]-m[dst]); z[dst] += p[i]
__global__ void n_z(const int* __restrict__ ei, const float* __restrict__ e,
                    const unsigned* __restrict__ mkey, float* __restrict__ p,
                    float* __restrict__ z, int E, int ET){
    int i = blockIdx.x*256 + threadIdx.x;
    if (i >= ET) return;
    int dst = (i < E) ? ei[E + i] : (i - E);
    float pv = expf(e[i] - funkey(mkey[dst]));
    p[i] = pv;
    atomicAdd(&z[dst], pv);
}

// out[dst][c] += (p[i]/(z[dst]+1e-16)) * h[src][c]  — wave per edge, lane=channel
__global__ void n_agg64(const int* __restrict__ ei, const float* __restrict__ p,
                        const float* __restrict__ z, const float* __restrict__ h,
                        float* __restrict__ outacc, int E, int ET){
    int gid = blockIdx.x*256 + threadIdx.x;
    int i = gid >> 6, lane = gid & 63;
    if (i >= ET) return;
    int src = (i < E) ? ei[i]     : (i - E);
    int dst = (i < E) ? ei[E + i] : (i - E);
    float coef = p[i] / (z[dst] + 1e-16f);
    atomicAdd(&outacc[(size_t)dst*64 + lane], coef * h[(size_t)src*64 + lane]);
}

__global__ void n_finish1(float* __restrict__ out1, const float* __restrict__ b1, int N){
    int idx = blockIdx.x*256 + threadIdx.x;
    if (idx >= N*64) return;
    out1[idx] = fmaxf(out1[idx] + b1[idx & 63], 0.f);
}

__global__ void n_gemm2(const float* __restrict__ xin, const float* __restrict__ W2,
                        float* __restrict__ h2, int N){
    int idx = blockIdx.x*256 + threadIdx.x;
    if (idx >= N*16) return;
    int n = idx >> 4, c = idx & 15;
    const float* xr = xin + (size_t)n*64;
    float acc = 0.f;
    for (int i = 0; i < 64; ++i) acc = fmaf(xr[i], W2[i*16 + c], acc);
    h2[idx] = acc;
}

// 16-lane-group per edge
__global__ void n_agg16(const int* __restrict__ ei, const float* __restrict__ p,
                        const float* __restrict__ z, const float* __restrict__ h,
                        float* __restrict__ outacc, int E, int ET){
    int gid = blockIdx.x*256 + threadIdx.x;
    int i = gid >> 4, c = gid & 15;
    if (i >= ET) return;
    int src = (i < E) ? ei[i]     : (i - E);
    int dst = (i < E) ? ei[E + i] : (i - E);
    float coef = p[i] / (z[dst] + 1e-16f);
    atomicAdd(&outacc[(size_t)dst*16 + c], coef * h[(size_t)src*16 + c]);
}

// bias + log_softmax over 16 channels (thread per node)
__global__ void n_finish2(const float* __restrict__ acc2, const float* __restrict__ b2,
                          float* __restrict__ out, int N){
    int n = blockIdx.x*256 + threadIdx.x;
    if (n >= N) return;
    float o[16];
    float mx = -1e30f;
    #pragma unroll
    for (int c = 0; c < 16; ++c){ o[c] = acc2[(size_t)n*16 + c] + b2[c]; mx = fmaxf(mx, o[c]); }
    float sum = 0.f;
    #pragma unroll
    for (int c = 0; c < 16; ++c) sum += expf(o[c] - mx);
    float ls = logf(sum);
    #pragma unroll
    for (int c = 0; c < 16; ++c) out[(size_t)n*16 + c] = o[c] - mx - ls;
}

extern "C" void kernel_launch(void* const* d_in, const int* in_sizes, int n_in,
                              void* d_out, int out_size, void* d_ws, size_t ws_size,
                              hipStream_t stream)
{
    const float* x      = (const float*)d_in[0];
    const int*   ei     = (const int*)d_in[1];
    const float* W1     = (const float*)d_in[2];
    const float* a_src1 = (const float*)d_in[3];
    const float* a_dst1 = (const float*)d_in[4];
    const float* b1     = (const float*)d_in[5];
    const float* W2     = (const float*)d_in[6];
    const float* a_src2 = (const float*)d_in[7];
    const float* a_dst2 = (const float*)d_in[8];
    const float* b2     = (const float*)d_in[9];
    float* out = (float*)d_out;
    const int N  = in_sizes[0] / 128;
    const int E  = in_sizes[1] / 2;
    const int ET = E + N;   // real edges + self-loops

    char* ptr = (char*)d_ws;
    auto alloc = [&](size_t bytes)->char* {
        char* r = ptr; ptr += (bytes + 255) & ~(size_t)255; return r;
    };
    float*    h1    = (float*)alloc((size_t)N*64*4);
    float*    out1  = (float*)alloc((size_t)N*64*4);   // agg accumulator then relu'd features
    float*    h2    = (float*)alloc((size_t)N*16*4);
    float*    agg2  = (float*)alloc((size_t)N*16*4);
    float*    sbuf  = (float*)alloc((size_t)N*4);
    float*    dbuf  = (float*)alloc((size_t)N*4);
    float*    zbuf  = (float*)alloc((size_t)N*4);
    unsigned* mkey  = (unsigned*)alloc((size_t)N*4);
    float*    ebuf  = (float*)alloc((size_t)ET*4);
    float*    pbuf  = (float*)alloc((size_t)ET*4);

    const int gN    = (N + 255)/256;
    const int gN64  = ((size_t)N*64 + 255)/256;
    const int gN16  = ((size_t)N*16 + 255)/256;
    const int gET   = (ET + 255)/256;
    const int gET64 = ((size_t)ET*64 + 255)/256;
    const int gET16 = ((size_t)ET*16 + 255)/256;

    // ---------- layer 1 ----------
    hipMemsetAsync(mkey, 0, (size_t)N*4, stream);
    hipMemsetAsync(zbuf, 0, (size_t)N*4, stream);
    hipMemsetAsync(out1, 0, (size_t)N*64*4, stream);
    n_gemm1<<<gN64, 256, 0, stream>>>(x, W1, h1, N);
    n_sd   <<<gN,   256, 0, stream>>>(h1, a_src1, a_dst1, sbuf, dbuf, N, 64);
    n_score<<<gET,  256, 0, stream>>>(ei, sbuf, dbuf, ebuf, mkey, E, ET);
    n_z    <<<gET,  256, 0, stream>>>(ei, ebuf, mkey, pbuf, zbuf, E, ET);
    n_agg64<<<gET64,256, 0, stream>>>(ei, pbuf, zbuf, h1, out1, E, ET);
    n_finish1<<<gN64,256, 0, stream>>>(out1, b1, N);

    // ---------- layer 2 ----------
    hipMemsetAsync(mkey, 0, (size_t)N*4, stream);
    hipMemsetAsync(zbuf, 0, (size_t)N*4, stream);
    hipMemsetAsync(agg2, 0, (size_t)N*16*4, stream);
    n_gemm2<<<gN16, 256, 0, stream>>>(out1, W2, h2, N);
    n_sd   <<<gN,   256, 0, stream>>>(h2, a_src2, a_dst2, sbuf, dbuf, N, 16);
    n_score<<<gET,  256, 0, stream>>>(ei, sbuf, dbuf, ebuf, mkey, E, ET);
    n_z    <<<gET,  256, 0, stream>>>(ei, ebuf, mkey, pbuf, zbuf, E, ET);
    n_agg16<<<gET16,256, 0, stream>>>(ei, pbuf, zbuf, h2, agg2, E, ET);
    n_finish2<<<gN, 256, 0, stream>>>(agg2, b2, out, N);
}